// Round 7
// baseline (252.234 us; speedup 1.0000x reference)
//
#include <hip/hip_runtime.h>
#include <hip/hip_bf16.h>
#include <cstdint>
#include <cstddef>

#define B_  4
#define T_  2048
#define C_  768
#define NH_ 12
#define HD_ 64

typedef __bf16 bf16_t;
typedef __attribute__((ext_vector_type(8))) __bf16 bf16x8;
typedef __attribute__((ext_vector_type(4))) __bf16 bf16x4;
typedef __attribute__((ext_vector_type(4))) float floatx4;
typedef __attribute__((ext_vector_type(8))) unsigned short ushort8;

#define MFMA16(a, b, c) __builtin_amdgcn_mfma_f32_16x16x32_bf16((a), (b), (c), 0, 0, 0)

// exp2 constants: p = exp2(s_raw * 0.125 * log2e - 12 * log2e)
#define SM_C1 0.18033688f
#define SM_C2 -17.3123405f

typedef const __attribute__((address_space(1))) uint8_t* gptr_t;
typedef __attribute__((address_space(3))) uint8_t* lptr_t;

static __device__ __forceinline__ void gld16(const void* g, void* l) {
    // per-lane global address; LDS dest = wave-uniform base + lane*16
    __builtin_amdgcn_global_load_lds((gptr_t)g, (lptr_t)l, 16, 0, 0);
}

static __device__ __forceinline__ float bfl(unsigned p) {       // low bf16 -> f32
    return __builtin_bit_cast(float, p << 16);
}
static __device__ __forceinline__ float bfh(unsigned p) {       // high bf16 -> f32
    return __builtin_bit_cast(float, p & 0xffff0000u);
}

// ---------------------------------------------------------------------------
// fp32 fallback conversion only (bf16 case: all kernels read raw inputs).
// Discriminator: cos[0][0]==1.0 -> first u16 0x3F80 if bf16, 0x0000 if fp32.
// ---------------------------------------------------------------------------
__global__ __launch_bounds__(256) void cvt_all_kernel(
    const void* s0, const void* s1, const void* s2, const void* s3,
    const void* s4, const void* s5, const void* s6, const void* s7, const void* s8,
    bf16_t* d0, bf16_t* d1, bf16_t* d2, bf16_t* d3,
    bf16_t* d4, bf16_t* d5, bf16_t* d6, bf16_t* d7, bf16_t* d8)
{
    const bool isf32 = (((const unsigned short*)s2)[0] == 0);
    if (!isf32) return;
    const void* srcs[9] = {s0, s1, s2, s3, s4, s5, s6, s7, s8};
    bf16_t*     dsts[9] = {d0, d1, d2, d3, d4, d5, d6, d7, d8};
    const int   ns[9]   = {B_*T_*C_, B_*T_*C_, T_*32, T_*32,
                           C_*C_, C_*C_, C_*C_, C_*C_, 144};
    const int t = blockIdx.y;
    const float* sf = (const float*)srcs[t];
    bf16_t*     dst = dsts[t];
    const int   nc  = ns[t] >> 3;
    const int stride = gridDim.x * 256;
    for (int i = blockIdx.x * 256 + threadIdx.x; i < nc; i += stride) {
        ushort8 o;
#pragma unroll
        for (int j = 0; j < 8; j++)
            o[j] = (unsigned short)__builtin_bit_cast(unsigned short,
                     (bf16_t)sf[i * 8 + j]);
        *(ushort8*)&dst[i * 8] = o;
    }
}

// ---------------------------------------------------------------------------
// Fused QKV GEMM + rope/rms (Q,K) + gate/ve (V).
// 128x128 tile, BK=32 double-buffered pipeline (1 barrier/step, prefetch
// overlaps MFMA). Outputs: qn,kn [b][t][C]; vt [bh][d][t-perm].
// ---------------------------------------------------------------------------
__global__ __launch_bounds__(256) void gemm_qkv_fused(
    const void* xr,  const bf16_t* xc,
    const void* wqr, const bf16_t* wqc,
    const void* wkr, const bf16_t* wkc,
    const void* wvr, const bf16_t* wvc,
    const void* cr,  const bf16_t* ccv,
    const void* sr,  const bf16_t* scv,
    const void* ver, const bf16_t* vec,
    const void* wgr, const bf16_t* wgc,
    bf16_t* qn, bf16_t* kn, bf16_t* vt)
{
    __shared__ alignas(16) char sm[36864];
    const bool f32 = (((const unsigned short*)cr)[0] == 0);
    const bf16_t* X  = f32 ? xc  : (const bf16_t*)xr;
    const bf16_t* WQ = f32 ? wqc : (const bf16_t*)wqr;
    const bf16_t* WK = f32 ? wkc : (const bf16_t*)wkr;
    const bf16_t* WV = f32 ? wvc : (const bf16_t*)wvr;
    const bf16_t* CC = f32 ? ccv : (const bf16_t*)cr;
    const bf16_t* SS = f32 ? scv : (const bf16_t*)sr;
    const bf16_t* VE = f32 ? vec : (const bf16_t*)ver;
    const bf16_t* WG = f32 ? wgc : (const bf16_t*)wgr;

    const int sel = blockIdx.y / 6;          // 0=Q 1=K 2=V
    const int nt  = blockIdx.y % 6;
    const int m0  = blockIdx.x * 128;
    const int n0  = nt * 128;
    const bf16_t* Bm = (sel == 0) ? WQ : (sel == 1) ? WK : WV;

    bf16_t* As = (bf16_t*)sm;                // [2][128*32]
    bf16_t* Bs = (bf16_t*)(sm + 16384);      // [2][128*32]

    const int tid  = threadIdx.x;
    const int lane = tid & 63;
    const int wid  = tid >> 6;
    const int m16  = lane & 15;
    const int quad = lane >> 4;
    const int wm   = (wid >> 1) * 64;
    const int wn   = (wid & 1) * 64;
    const int srow = lane >> 2;
    const int soct = (lane & 3) * 8;

    floatx4 acc[4][4];
#pragma unroll
    for (int i = 0; i < 4; i++)
#pragma unroll
        for (int j = 0; j < 4; j++) acc[i][j] = (floatx4){0.f, 0.f, 0.f, 0.f};

    const bf16_t* ga = &X[(size_t)(m0 + 16 * wid + srow) * C_ + soct];
    const bf16_t* gb = &Bm[(size_t)(n0 + 16 * wid + srow) * C_ + soct];
    const int nsteps = C_ / 32;   // 24

    // prologue: stage step 0 into buf 0
    gld16(ga,                   As + wid * 512);
    gld16(ga + (size_t)64 * C_, As + wid * 512 + 2048);
    gld16(gb,                   Bs + wid * 512);
    gld16(gb + (size_t)64 * C_, Bs + wid * 512 + 2048);

    for (int s = 0; s < nsteps; s++) {
        __syncthreads();
        const int buf = s & 1;
        if (s + 1 < nsteps) {
            const int nb = buf ^ 1;
            const bf16_t* ga1 = ga + (s + 1) * 32;
            const bf16_t* gb1 = gb + (s + 1) * 32;
            gld16(ga1,                   As + nb * 4096 + wid * 512);
            gld16(ga1 + (size_t)64 * C_, As + nb * 4096 + wid * 512 + 2048);
            gld16(gb1,                   Bs + nb * 4096 + wid * 512);
            gld16(gb1 + (size_t)64 * C_, Bs + nb * 4096 + wid * 512 + 2048);
        }
        bf16x8 af[4], bfr[4];
#pragma unroll
        for (int i = 0; i < 4; i++)
            af[i] = *(const bf16x8*)&As[buf * 4096 + (wm + i * 16 + m16) * 32 + quad * 8];
#pragma unroll
        for (int j = 0; j < 4; j++)
            bfr[j] = *(const bf16x8*)&Bs[buf * 4096 + (wn + j * 16 + m16) * 32 + quad * 8];
#pragma unroll
        for (int i = 0; i < 4; i++)
#pragma unroll
            for (int j = 0; j < 4; j++)
                acc[i][j] = MFMA16(af[i], bfr[j], acc[i][j]);
    }
    __syncthreads();   // all waves done with As/Bs before LDS reuse below

    if (sel < 2) {
        // ---- Q/K epilogue: rope + rms, store [b][t][C] ----
        unsigned* csT = (unsigned*)sm;       // [128][33] packed (cos | sin<<16)
        const int tbase = m0 & 2047;
        for (int idx = tid; idx < 128 * 32; idx += 256) {
            const int rr = idx >> 5, dd = idx & 31;
            const unsigned cv = ((const unsigned short*)CC)[(tbase + rr) * 32 + dd];
            const unsigned sv = ((const unsigned short*)SS)[(tbase + rr) * 32 + dd];
            csT[rr * 33 + dd] = cv | (sv << 16);
        }
        __syncthreads();
        bf16_t* OUT = (sel == 0) ? qn : kn;
#pragma unroll
        for (int i = 0; i < 4; i++) {
            float c0[4], s0[4], c1[4], s1[4];
#pragma unroll
            for (int r = 0; r < 4; r++) {
                const int rl = wm + i * 16 + quad * 4 + r;
                const unsigned p0 = csT[rl * 33 + m16];
                const unsigned p1 = csT[rl * 33 + 16 + m16];
                c0[r] = bfl(p0); s0[r] = bfh(p0);
                c1[r] = bfl(p1); s1[r] = bfh(p1);
            }
            floatx4 r0, r1, r2, r3;
            float ss[4];
#pragma unroll
            for (int r = 0; r < 4; r++) {
                r0[r] = acc[i][0][r] * c0[r] - acc[i][2][r] * s0[r];
                r1[r] = acc[i][1][r] * c1[r] - acc[i][3][r] * s1[r];
                r2[r] = acc[i][0][r] * s0[r] + acc[i][2][r] * c0[r];
                r3[r] = acc[i][1][r] * s1[r] + acc[i][3][r] * c1[r];
                ss[r] = r0[r]*r0[r] + r1[r]*r1[r] + r2[r]*r2[r] + r3[r]*r3[r];
            }
#pragma unroll
            for (int r = 0; r < 4; r++) {
#pragma unroll
                for (int off = 1; off < 16; off <<= 1)
                    ss[r] += __shfl_xor(ss[r], off, 64);
            }
#pragma unroll
            for (int r = 0; r < 4; r++) {
                const float scl = rsqrtf(ss[r] * (1.f / 64.f) + 1e-6f) * 1.2f;
                const size_t rowoff = (size_t)(m0 + wm + i * 16 + quad * 4 + r) * C_
                                      + n0 + wn + m16;
                OUT[rowoff]      = (bf16_t)(r0[r] * scl);
                OUT[rowoff + 16] = (bf16_t)(r1[r] * scl);
                OUT[rowoff + 32] = (bf16_t)(r2[r] * scl);
                OUT[rowoff + 48] = (bf16_t)(r3[r] * scl);
            }
        }
    } else {
        // ---- V epilogue: gate + ve add + direct permuted store ----
        // veT pitch 140 (280B = 6 dwords mod 32): quad rows {0,4,8,12} land on
        // bank octets {0,24,16,8} -> conflict-free column reads.
        bf16_t* veT = (bf16_t*)sm;             // [128 tok][140]
        float*  gT  = (float*)(sm + 35840);    // [2][128]
        for (int idx = tid; idx < 2048; idx += 256) {
            const int rr = idx >> 4, ch = idx & 15;
            const bf16x8 v8 = *(const bf16x8*)&VE[(size_t)(m0 + rr) * C_ + n0 + ch * 8];
            bf16_t* p = &veT[rr * 140 + ch * 8];
            *(bf16x4*)p       = (bf16x4){v8[0], v8[1], v8[2], v8[3]};
            *(bf16x4*)(p + 4) = (bf16x4){v8[4], v8[5], v8[6], v8[7]};
        }
        {
            const int row = tid & 127, hh = tid >> 7;
            const int head = nt * 2 + hh;
            float g = 0.f;
#pragma unroll
            for (int j2 = 0; j2 < 12; j2++)
                g += (float)X[(size_t)(m0 + row) * C_ + j2] * (float)WG[head * 12 + j2];
            gT[hh * 128 + row] = 3.f / (1.f + __expf(-g));
        }
        __syncthreads();
        const int hh2  = wn >> 6;
        const int head = nt * 2 + hh2;
        const int bb = m0 >> 11, t0 = m0 & 2047;
#pragma unroll
        for (int i = 0; i < 4; i++) {
            const floatx4 gr = *(const floatx4*)&gT[hh2 * 128 + wm + i * 16 + quad * 4];
            const int tslot = t0 + wm + (i >> 1) * 32 + quad * 8 + (i & 1) * 4;
#pragma unroll
            for (int j = 0; j < 4; j++) {
                bf16x4 o;
#pragma unroll
                for (int r = 0; r < 4; r++) {
                    const float vef = (float)veT[(wm + i * 16 + quad * 4 + r) * 140
                                                 + wn + j * 16 + m16];
                    o[r] = (bf16_t)(acc[i][j][r] + gr[r] * vef);
                }
                *(bf16x4*)&vt[((size_t)(bb * NH_ + head) * HD_ + j * 16 + m16) * T_
                              + tslot] = o;
            }
        }
    }
}

// ---------------------------------------------------------------------------
// Output-projection GEMM, same BK=32 double-buffered pipeline.
// ---------------------------------------------------------------------------
template <bool OUT_BF16>
__device__ __forceinline__ void gemm_bt_tile(
    const bf16_t* __restrict__ A, const bf16_t* __restrict__ Bm,
    void* __restrict__ Cout, int m0, int n0, int K, int ldc)
{
    __shared__ bf16_t As[2][128 * 32];
    __shared__ bf16_t Bs[2][128 * 32];
    const int tid  = threadIdx.x;
    const int lane = tid & 63;
    const int wid  = tid >> 6;
    const int m16  = lane & 15;
    const int quad = lane >> 4;
    const int wm   = (wid >> 1) * 64;
    const int wn   = (wid & 1) * 64;
    const int srow = lane >> 2;
    const int soct = (lane & 3) * 8;

    floatx4 acc[4][4];
#pragma unroll
    for (int i = 0; i < 4; i++)
#pragma unroll
        for (int j = 0; j < 4; j++) acc[i][j] = (floatx4){0.f, 0.f, 0.f, 0.f};

    const bf16_t* ga = &A[(size_t)(m0 + 16 * wid + srow) * K + soct];
    const bf16_t* gb = &Bm[(size_t)(n0 + 16 * wid + srow) * K + soct];
    const int nsteps = K / 32;

    gld16(ga,                  (bf16_t*)As[0] + wid * 512);
    gld16(ga + (size_t)64 * K, (bf16_t*)As[0] + wid * 512 + 2048);
    gld16(gb,                  (bf16_t*)Bs[0] + wid * 512);
    gld16(gb + (size_t)64 * K, (bf16_t*)Bs[0] + wid * 512 + 2048);

    for (int s = 0; s < nsteps; s++) {
        __syncthreads();
        const int buf = s & 1;
        if (s + 1 < nsteps) {
            const int nb = buf ^ 1;
            const bf16_t* ga1 = ga + (s + 1) * 32;
            const bf16_t* gb1 = gb + (s + 1) * 32;
            gld16(ga1,                  (bf16_t*)As[nb] + wid * 512);
            gld16(ga1 + (size_t)64 * K, (bf16_t*)As[nb] + wid * 512 + 2048);
            gld16(gb1,                  (bf16_t*)Bs[nb] + wid * 512);
            gld16(gb1 + (size_t)64 * K, (bf16_t*)Bs[nb] + wid * 512 + 2048);
        }
        bf16x8 af[4], bfr[4];
#pragma unroll
        for (int i = 0; i < 4; i++)
            af[i] = *(const bf16x8*)&As[buf][(wm + i * 16 + m16) * 32 + quad * 8];
#pragma unroll
        for (int j = 0; j < 4; j++)
            bfr[j] = *(const bf16x8*)&Bs[buf][(wn + j * 16 + m16) * 32 + quad * 8];
#pragma unroll
        for (int i = 0; i < 4; i++)
#pragma unroll
            for (int j = 0; j < 4; j++)
                acc[i][j] = MFMA16(af[i], bfr[j], acc[i][j]);
    }
#pragma unroll
    for (int i = 0; i < 4; i++) {
#pragma unroll
        for (int j = 0; j < 4; j++) {
            const int colg = n0 + wn + j * 16 + m16;
#pragma unroll
            for (int r = 0; r < 4; r++) {
                const int rowg = m0 + wm + i * 16 + quad * 4 + r;
                if (OUT_BF16)
                    ((bf16_t*)Cout)[(size_t)rowg * ldc + colg] = (bf16_t)acc[i][j][r];
                else
                    ((float*)Cout)[(size_t)rowg * ldc + colg] = acc[i][j][r];
            }
        }
    }
}

__global__ __launch_bounds__(256) void gemm_proj_kernel(
    const bf16_t* __restrict__ yb, const void* wpr, const bf16_t* wpc,
    void* __restrict__ out, const void* cr)
{
    const bool f32 = (((const unsigned short*)cr)[0] == 0);
    const bf16_t* WP = f32 ? wpc : (const bf16_t*)wpr;
    if (f32)
        gemm_bt_tile<false>(yb, WP, out, blockIdx.x * 128, blockIdx.y * 128, C_, C_);
    else
        gemm_bt_tile<true>(yb, WP, out, blockIdx.x * 128, blockIdx.y * 128, C_, C_);
}

// ---------------------------------------------------------------------------
// Flash attention (round-6-proven, unchanged). Fixed-SMAX softmax,
// S^T-in-register P, paired-K=32 PV, register staging + XOR-swizzled LDS.
// ---------------------------------------------------------------------------
__global__ __launch_bounds__(256, 3) void attn_kernel(
    const bf16_t* __restrict__ Q, const bf16_t* __restrict__ Km,
    const bf16_t* __restrict__ Vtg, bf16_t* __restrict__ Y,
    const int* __restrict__ wl)
{
    const int bx   = blockIdx.x;
    const int bh   = blockIdx.y;
    const int gsel = bh >> 4;
    int qblk;
    if (gsel == 0)      qblk = bx;
    else if (gsel == 1) qblk = 15 - bx;
    else                qblk = (int)((0xECA8642013579BDFull >> (bx * 4)) & 0xF);
    const int q0 = qblk * 128;
    const int b  = bh / NH_;
    const int h  = bh % NH_;
    const int window = wl[0];
    const int tid  = threadIdx.x;
    const int wid  = tid >> 6;
    const int lane = tid & 63;
    const int m16  = lane & 15;
    const int quad = lane >> 4;
    const int qw   = q0 + wid * 32;

    const bf16_t* Qb = Q + (size_t)b * T_ * C_ + h * HD_;   // row stride C_
    const bf16_t* Kb = Km + (size_t)b * T_ * C_ + h * HD_;
    const bf16_t* Vb = Vtg + (size_t)bh * HD_ * T_;         // [d][t-perm]

    __shared__ bf16_t Ks[2][64 * 64];
    __shared__ bf16_t Vs[2][64 * 64];

    bf16x8 qf[2][2];
#pragma unroll
    for (int mt = 0; mt < 2; mt++)
#pragma unroll
        for (int ks = 0; ks < 2; ks++)
            qf[mt][ks] = *(const bf16x8*)
                &Qb[(size_t)(qw + mt * 16 + m16) * C_ + ks * 32 + quad * 8];

    const int srow = tid >> 2;
    const int soct = tid & 3;
    const int g0   = 2 * soct, g1 = 2 * soct + 1;
    const int kd0  = srow * 64 + ((g0 ^ (srow & 7)) << 3);
    const int kd1  = srow * 64 + ((g1 ^ (srow & 7)) << 3);
    int rsw[2];
#pragma unroll
    for (int ks = 0; ks < 2; ks++)
        rsw[ks] = (((ks * 4 + quad) ^ (m16 & 7)) << 3);

    int lo = q0 - window;
    if (lo < 0) lo = 0;
    lo &= ~63;
    const int nch = (q0 + 128 - lo) >> 6;

    floatx4 accO[2][4];
#pragma unroll
    for (int mt = 0; mt < 2; mt++)
#pragma unroll
        for (int dt = 0; dt < 4; dt++) accO[mt][dt] = (floatx4){0.f, 0.f, 0.f, 0.f};
    float lsum[2] = {0.f, 0.f};
    const bf16x4 zero4 = {(bf16_t)0.f, (bf16_t)0.f, (bf16_t)0.f, (bf16_t)0.f};

    bf16x8 ka0 = *(const bf16x8*)&Kb[(size_t)(lo + srow) * C_ + g0 * 8];
    bf16x8 ka1 = *(const bf16x8*)&Kb[(size_t)(lo + srow) * C_ + g1 * 8];
    bf16x8 va0 = *(const bf16x8*)&Vb[(size_t)srow * T_ + lo + g0 * 8];
    bf16x8 va1 = *(const bf16x8*)&Vb[(size_t)srow * T_ + lo + g1 * 8];
    *(bf16x8*)&Ks[0][kd0] = ka0;
    *(bf16x8*)&Ks[0][kd1] = ka1;
    *(bf16x8*)&Vs[0][kd0] = va0;
    *(bf16x8*)&Vs[0][kd1] = va1;

    for (int ic = 0; ic < nch; ic++) {
        const int kc = lo + ic * 64;
        const bool more = (ic + 1 < nch);
        if (more) {
            const int kn2 = kc + 64;
            ka0 = *(const bf16x8*)&Kb[(size_t)(kn2 + srow) * C_ + g0 * 8];
            ka1 = *(const bf16x8*)&Kb[(size_t)(kn2 + srow) * C_ + g1 * 8];
            va0 = *(const bf16x8*)&Vb[(size_t)srow * T_ + kn2 + g0 * 8];
            va1 = *(const bf16x8*)&Vb[(size_t)srow * T_ + kn2 + g1 * 8];
        }
        __syncthreads();
        const int buf = ic & 1;

        const bool skip = (kc > qw + 31) || (kc + 63 < qw - window);
        if (!skip) {
            bf16x8 kf[4][2];
#pragma unroll
            for (int nt = 0; nt < 4; nt++) {
                const int rb = (nt * 16 + m16) * 64;
                kf[nt][0] = *(const bf16x8*)&Ks[buf][rb + rsw[0]];
                kf[nt][1] = *(const bf16x8*)&Ks[buf][rb + rsw[1]];
            }
            bf16x4 pk[2][4];
            unsigned livemask = 0;
#pragma unroll
            for (int mt = 0; mt < 2; mt++) {
                const int qmin = qw + mt * 16, qmax = qmin + 15;
                float lacc = 0.f;
#pragma unroll
                for (int nt = 0; nt < 4; nt++) {
                    const int kmin = kc + nt * 16, kmax = kmin + 15;
                    if (kmin > qmax || kmax < qmin - window) {
                        pk[mt][nt] = zero4;
                        continue;
                    }
                    livemask |= 1u << (mt * 4 + nt);
                    floatx4 z = (floatx4){0.f, 0.f, 0.f, 0.f};
                    z = MFMA16(kf[nt][0], qf[mt][0], z);
                    z = MFMA16(kf[nt][1], qf[mt][1], z);
                    const bool edge = (kmax > qmin) || (kmin < qmax - window);
                    const int query = qmin + m16;
                    bf16x4 t4;
#pragma unroll
                    for (int r = 0; r < 4; r++) {
                        float p = __builtin_amdgcn_exp2f(
                            fmaf(z[r], SM_C1, SM_C2));
                        if (edge) {
                            const int key = kmin + quad * 4 + r;
                            const bool ok = (key <= query) &&
                                            (query - key <= window);
                            p = ok ? p : 0.f;
                        }
                        t4[r] = (bf16_t)p;
                        lacc += p;
                    }
                    pk[mt][nt] = t4;
                }
                lsum[mt] += lacc;
            }
#pragma unroll
            for (int pr = 0; pr < 2; pr++) {
                const unsigned pm0 = (livemask >> (2 * pr)) & 3u;
                const unsigned pm1 = (livemask >> (4 + 2 * pr)) & 3u;
                if (!(pm0 | pm1)) continue;
                const bf16x8 pa0 = __builtin_shufflevector(
                    pk[0][2 * pr], pk[0][2 * pr + 1], 0, 1, 2, 3, 4, 5, 6, 7);
                const bf16x8 pa1 = __builtin_shufflevector(
                    pk[1][2 * pr], pk[1][2 * pr + 1], 0, 1, 2, 3, 4, 5, 6, 7);
                const int vco = (((pr * 4 + quad) ^ (m16 & 7)) << 3);
#pragma unroll
                for (int dt = 0; dt < 4; dt++) {
                    const bf16x8 vf = *(const bf16x8*)
                        &Vs[buf][(dt * 16 + m16) * 64 + vco];
                    if (pm0) accO[0][dt] = MFMA16(pa0, vf, accO[0][dt]);
                    if (pm1) accO[1][dt] = MFMA16(pa1, vf, accO[1][dt]);
                }
            }
        }

        if (more) {
            const int nb = buf ^ 1;
            *(bf16x8*)&Ks[nb][kd0] = ka0;
            *(bf16x8*)&Ks[nb][kd1] = ka1;
            *(bf16x8*)&Vs[nb][kd0] = va0;
            *(bf16x8*)&Vs[nb][kd1] = va1;
        }
    }

#pragma unroll
    for (int mt = 0; mt < 2; mt++) {
        float red = lsum[mt];
        red += __shfl_xor(red, 16, 64);
        red += __shfl_xor(red, 32, 64);
#pragma unroll
        for (int r = 0; r < 4; r++) {
            const float lq  = __shfl(red, quad * 4 + r, 64);
            const float inv = 1.f / lq;
            const int   tq  = qw + mt * 16 + quad * 4 + r;
#pragma unroll
            for (int dt = 0; dt < 4; dt++)
                Y[((size_t)b * T_ + tq) * C_ + h * HD_ + dt * 16 + m16] =
                    (bf16_t)(accO[mt][dt][r] * inv);
        }
    }
}

// ---------------------------------------------------------------------------
extern "C" void kernel_launch(void* const* d_in, const int* in_sizes, int n_in,
                              void* d_out, int out_size, void* d_ws, size_t ws_size,
                              hipStream_t stream)
{
    const void* x_raw   = d_in[0];
    const void* ve_raw  = d_in[1];
    const void* cos_raw = d_in[2];
    const void* sin_raw = d_in[3];
    const void* wq_raw  = d_in[4];
    const void* wk_raw  = d_in[5];
    const void* wv_raw  = d_in[6];
    const void* wp_raw  = d_in[7];
    const void* wg_raw  = d_in[8];
    const int*  wl      = (const int*)d_in[9];

    const size_t NTC = (size_t)B_ * T_ * C_;  // 6291456
    const size_t WSZ = (size_t)C_ * C_;       // 589824

    bf16_t* ws  = (bf16_t*)d_ws;
    bf16_t* xb  = ws;                 // NTC   (fp32-cvt targets)
    bf16_t* veb = xb + NTC;           // NTC
    bf16_t* cb  = veb + NTC;          // 65536
    bf16_t* sb  = cb + T_ * 32;       // 65536
    bf16_t* wqb = sb + T_ * 32;       // WSZ x4
    bf16_t* wkb = wqb + WSZ;
    bf16_t* wvb = wkb + WSZ;
    bf16_t* wpb = wvb + WSZ;
    bf16_t* wgb = wpb + WSZ;          // 144 (pad 256)
    bf16_t* qn  = wgb + 256;          // NTC  rope+rms Q  [b][t][C]
    bf16_t* kn  = qn + NTC;           // NTC  rope+rms K  [b][t][C]
    bf16_t* vt  = kn + NTC;           // NTC  V^T [bh][d][t-perm]
    bf16_t* yb  = vt + NTC;           // NTC  attention out [b][t][C]

    cvt_all_kernel<<<dim3(128, 9), 256, 0, stream>>>(
        x_raw, ve_raw, cos_raw, sin_raw, wq_raw, wk_raw, wv_raw, wp_raw, wg_raw,
        xb, veb, cb, sb, wqb, wkb, wvb, wpb, wgb);

    gemm_qkv_fused<<<dim3(64, 18), 256, 0, stream>>>(
        x_raw, xb, wq_raw, wqb, wk_raw, wkb, wv_raw, wvb,
        cos_raw, cb, sin_raw, sb, ve_raw, veb, wg_raw, wgb,
        qn, kn, vt);

    attn_kernel<<<dim3(16, 48), 256, 0, stream>>>(qn, kn, vt, yb, wl);

    gemm_proj_kernel<<<dim3(64, 6), 256, 0, stream>>>(yb, wp_raw, wpb, d_out, cos_raw);
}